// Round 8
// baseline (162.198 us; speedup 1.0000x reference)
//
#include <hip/hip_runtime.h>
#include <cstdint>

#define BATCH   8192
#define KDIM    256
#define HID     64
#define NODES   255
#define NPG     4     // nodes per block group (tail-friendly at 3 blocks/CU)

typedef unsigned short u16;
typedef unsigned int u32;
typedef short bf16x8 __attribute__((ext_vector_type(8)));
typedef float f32x16 __attribute__((ext_vector_type(16)));

// ---- helpers ---------------------------------------------------------------

__device__ __forceinline__ u32 f2bf(float f) {
  u32 u = __float_as_uint(f);
  return (u + 0x7FFFu + ((u >> 16) & 1u)) >> 16;
}

__device__ __forceinline__ void gld_lds16(const void* g, void* l) {
  // async global->LDS, 16B/lane; LDS dest = wave-uniform base + lane*16
  typedef __attribute__((address_space(1))) void* gp_t;
  typedef __attribute__((address_space(3))) void* lp_t;
  gp_t gp = reinterpret_cast<gp_t>(reinterpret_cast<uintptr_t>(g));
  lp_t lp = reinterpret_cast<lp_t>(static_cast<u32>(reinterpret_cast<uintptr_t>(l)));
  __builtin_amdgcn_global_load_lds(gp, lp, 16, 0, 0);
}

// ---- kernel 1: convert + pack ----------------------------------------------
// blocks [0,256):   x -> xpack (B-fragment granule order) via LDS transpose
// blocks [256,511): w1 -> w1pk, K-MAJOR granules: granule(node,kb,h) at
//                   node*2048 + kb*64 + h -> staging = identity copy
// blocks [511,639): w2/b1 permute into MFMA C/D register order
// (VERIFIED — byte-identical to the R10/R14 passing rounds.)

#define NPRM 16320     // 255*64

__global__ __launch_bounds__(256) void cvt_kernel(
    const float* __restrict__ x, const float* __restrict__ w1,
    const float* __restrict__ b1, const float* __restrict__ w2,
    u16* __restrict__ xpack, u16* __restrict__ w1pk,
    float* __restrict__ b1p, float* __restrict__ w2p) {
  const int tid = threadIdx.x;
  const int blk = blockIdx.x;

  if (blk < 256) {
    __shared__ u16 sT[32 * 268];
    const float* xs = x + (size_t)blk * 32 * KDIM;
#pragma unroll
    for (int j = 0; j < 8; ++j) {
      int idx = j * 256 + tid;
      float4 v = ((const float4*)xs)[idx];
      int row = idx >> 6, f4 = idx & 63;
      *(u32*)&sT[row * 268 + f4 * 4]     = f2bf(v.x) | (f2bf(v.y) << 16);
      *(u32*)&sT[row * 268 + f4 * 4 + 2] = f2bf(v.z) | (f2bf(v.w) << 16);
    }
    __syncthreads();
#pragma unroll
    for (int j = 0; j < 4; ++j) {
      int d = j * 256 + tid;               // granule: ks*64 + hl*32 + l31
      int ks = d >> 6, hl = (d >> 5) & 1, l31 = d & 31;
      const u16* s8 = &sT[l31 * 268 + ks * 16 + hl * 8];
      u32 a = *(const u32*)s8, b = *(const u32*)(s8 + 2);
      u32 c = *(const u32*)(s8 + 4), e = *(const u32*)(s8 + 6);
      uint4 o = {a, b, c, e};
      ((uint4*)xpack)[(size_t)blk * 1024 + d] = o;
    }
  } else if (blk < 511) {
    __shared__ u16 sT[64 * 260];
    const int node = blk - 256;
    const float* src = w1 + (size_t)node * (HID * KDIM);
#pragma unroll
    for (int r = 0; r < 16; ++r) {
      int idx = r * 256 + tid;
      float4 v = ((const float4*)src)[idx];
      int h = idx >> 6, f4 = idx & 63;
      uint2 o;
      o.x = f2bf(v.x) | (f2bf(v.y) << 16);
      o.y = f2bf(v.z) | (f2bf(v.w) << 16);
      *(uint2*)&sT[h * 260 + f4 * 4] = o;
    }
    __syncthreads();
    u16* dst = w1pk + (size_t)node * (HID * KDIM);
#pragma unroll
    for (int r = 0; r < 8; ++r) {
      int g = r * 256 + tid;
      int kb = g >> 6, h = g & 63;
      const u16* s8 = &sT[h * 260 + kb * 8];
      uint2 lo = *(const uint2*)s8;
      uint2 hi = *(const uint2*)(s8 + 4);
      uint4 o = {lo.x, lo.y, hi.x, hi.y};
      ((uint4*)dst)[g] = o;
    }
  } else {
    int i2 = (blk - 511) * 256 + tid;
    if (i2 < 2 * NPRM) {
      int a = i2 >= NPRM;
      int j = a ? i2 - NPRM : i2;
      int reg = j & 15, rt = (j >> 4) & 1, hl = (j >> 5) & 1, node = j >> 6;
      int h = rt * 32 + (reg & 3) + 8 * (reg >> 2) + 4 * hl;
      float v = (a ? b1 : w2)[node * 64 + h];
      (a ? b1p : w2p)[j] = v;
    }
  }
}

// ---- kernel 2: fused MLP ---------------------------------------------------
// R16: 3 blocks/CU via K-split xf. R14 accounting: per SIMD, matrix 65.5k +
// VALU 46.4k + DS 12.3k cyc ~= 52us of the 64us wall with ~zero overlap —
// 2 phase-heavy waves/SIMD can't cover each other's dependency chains. All
// intra-block scheduling fixes were null; the lever is a 3rd independent
// wave per SIMD. Register diet to <=170 (512/3):
//  - xf holds HALF the K at a time: xf0/xf1[8] = 64 VGPR (was 128).
//  - Per-node ALTERNATING K-half order (even nodes K0->K1, odd K1->K0;
//    fp32-accum reorder harmless) -> xf already holds the right half at
//    every node boundary; exactly ONE rolling reload per node, issued
//    ks-granular inside phase 1 (WAR deps sequence loads after last use;
//    L2-hit, ~250cyc, covered by phase-1 MFMAs).
//  - acc 64 + xf 64 + transients ~35 = ~163 regs.
// Stages become 16KB K-halves of the UNCHANGED K-major w1pk (half = kb<16
// is contiguous). Plain __syncthreads only (counted-vmcnt idiom was the
// prime suspect in R15's corruption; R14 measured it as null anyway).
// LDS 2x16KB + 2x1KB = 34.8KB -> 3 blocks/CU (105KB). NPG=4, grid 32x64.

__global__ __launch_bounds__(256, 3) void fused_mlp_kernel(
    const u16* __restrict__ xpack,  // packed B-frag granules
    const u16* __restrict__ w1pk,   // [256(pad)][32 kb][64 h] granules
    const float* __restrict__ b1p,  // [255][2 hl][2 ht][16] permuted
    const float* __restrict__ w2p,  // [255][2 hl][2 ht][16] permuted
    const float* __restrict__ b2,   // [255]
    float* __restrict__ no_t)       // [255][8192] node_outputs transposed
{
  __shared__ __align__(16) u16 sW[2][8192];        // 2 x 16 KB (K-half)
  __shared__ __align__(16) float sW2[NPG * 64];    // 1 KB
  __shared__ __align__(16) float sB1[NPG * 64];    // 1 KB

  const int tid  = threadIdx.x;
  const int lane = tid & 63;
  const int wv   = tid >> 6;
  const int l31  = lane & 31;
  const int hl   = lane >> 5;
  const int nbase = blockIdx.y * NPG;

  // stage one K-half (1024 granules = 16 KB): identity copy.
  // K-major w1pk => half h of node n is contiguous at n*16384 + h*8192 u16.
  auto stage_half = [&](int iLocal, int half, int bufIdx) {
    const u16* base = w1pk + (size_t)(nbase + iLocal) * 16384 + half * 8192;
    char* lb = (char*)(&sW[bufIdx][0]);
#pragma unroll
    for (int j = 0; j < 4; ++j) {
      int s = j * 256 + tid;
      gld_lds16(base + s * 8, lb + s * 16);
    }
  };

  stage_half(0, 0, 0);                 // phase 0 content: node 0, half 0
  if (tid < 64) {
    gld_lds16(w2p + (size_t)nbase * 64 + tid * 4, (char*)sW2 + tid * 16);
  } else if (tid < 128) {
    int t = tid - 64;
    gld_lds16(b1p + (size_t)nbase * 64 + t * 4, (char*)sB1 + t * 16);
  }

  // ---- x fragments: 2 col-tiles x 8 ks (HALF of K), coalesced ----
  const int ctile0 = blockIdx.x * 8 + wv * 2;
  const u16* xs0 = xpack + (size_t)(ctile0 + 0) * 8192 + lane * 8;
  const u16* xs1 = xpack + (size_t)(ctile0 + 1) * 8192 + lane * 8;
  bf16x8 xf0[8], xf1[8];               // current K-half (invariant: = i&1)
#pragma unroll
  for (int ks = 0; ks < 8; ++ks) {
    xf0[ks] = *(const bf16x8*)(xs0 + ks * 512);
    xf1[ks] = *(const bf16x8*)(xs1 + ks * 512);
  }

  // lane's a-frag base within a 16KB half: byte = ksl*2048 + hl*1024
  //   + ht*512 + l31*16 (kb_local = ksl*2 + hl, h = ht*32 + l31)
  const u32 abase = (u32)(hl * 64 + l31) * 16u;

  __syncthreads();  // phase-0 stage + wb stages drained

  for (int i = 0; i < NPG; ++i) {
    const int fc = i & 1;        // half used by phase 1 (== current xf)
    const int oc = fc ^ 1;       // half used by phase 2

    // ---- phase 1: reads sW[0] (half fc); stage phase-2 content ----
    stage_half(i, oc, 1);

    // acc init from bias (fold)
    f32x16 acc00, acc01, acc10, acc11;
    {
      const int o0 = i * 64 + hl * 32;
#pragma unroll
      for (int qd = 0; qd < 4; ++qd) {
        float4 b0  = *(const float4*)&sB1[o0 + qd * 4];        // ht=0 rows
        float4 b1q = *(const float4*)&sB1[o0 + 16 + qd * 4];   // ht=1 rows
#pragma unroll
        for (int e = 0; e < 4; ++e) {
          acc00[qd * 4 + e] = (&b0.x)[e];
          acc01[qd * 4 + e] = (&b0.x)[e];
          acc10[qd * 4 + e] = (&b1q.x)[e];
          acc11[qd * 4 + e] = (&b1q.x)[e];
        }
      }
    }

    {
      const char* sw = (const char*)&sW[0][0] + abase;
      const u16* nx0 = xs0 + oc * 4096;   // other K-half of X
      const u16* nx1 = xs1 + oc * 4096;
#pragma unroll
      for (int ks = 0; ks < 8; ++ks) {
        bf16x8 a0 = *(const bf16x8*)(sw + ks * 2048);        // ht=0
        bf16x8 a1 = *(const bf16x8*)(sw + ks * 2048 + 512);  // ht=1
        acc00 = __builtin_amdgcn_mfma_f32_32x32x16_bf16(a0, xf0[ks], acc00, 0, 0, 0);
        acc01 = __builtin_amdgcn_mfma_f32_32x32x16_bf16(a0, xf1[ks], acc01, 0, 0, 0);
        acc10 = __builtin_amdgcn_mfma_f32_32x32x16_bf16(a1, xf0[ks], acc10, 0, 0, 0);
        acc11 = __builtin_amdgcn_mfma_f32_32x32x16_bf16(a1, xf1[ks], acc11, 0, 0, 0);
        // rolling reload: WAR on xf regs orders these after the MFMAs above
        xf0[ks] = *(const bf16x8*)(nx0 + ks * 512);
        xf1[ks] = *(const bf16x8*)(nx1 + ks * 512);
      }
    }
    __syncthreads();   // phase-2 buffer staged; sW[0] readers done

    // ---- phase 2: reads sW[1] (half oc); stage next node's phase 1 ----
    if (i + 1 < NPG) stage_half(i + 1, oc, 0);   // next first-half == oc

    {
      const char* sw = (const char*)&sW[1][0] + abase;
#pragma unroll
      for (int ks = 0; ks < 8; ++ks) {
        bf16x8 a0 = *(const bf16x8*)(sw + ks * 2048);
        bf16x8 a1 = *(const bf16x8*)(sw + ks * 2048 + 512);
        acc00 = __builtin_amdgcn_mfma_f32_32x32x16_bf16(a0, xf0[ks], acc00, 0, 0, 0);
        acc01 = __builtin_amdgcn_mfma_f32_32x32x16_bf16(a0, xf1[ks], acc01, 0, 0, 0);
        acc10 = __builtin_amdgcn_mfma_f32_32x32x16_bf16(a1, xf0[ks], acc10, 0, 0, 0);
        acc11 = __builtin_amdgcn_mfma_f32_32x32x16_bf16(a1, xf1[ks], acc11, 0, 0, 0);
      }
    }

    // ---- epilogue: full logit, wave-local (R14-verbatim) ----
    float p0 = 0.f, p1 = 0.f;
#pragma unroll
    for (int qd = 0; qd < 4; ++qd) {
      int o = i * 64 + hl * 32 + qd * 4;
      float4 w0  = *(const float4*)&sW2[o];        // ht=0
      float4 w1q = *(const float4*)&sW2[o + 16];   // ht=1
#pragma unroll
      for (int e = 0; e < 4; ++e) {
        int r = qd * 4 + e;
        p0 += fmaxf(acc00[r], 0.f) * (&w0.x)[e];
        p1 += fmaxf(acc01[r], 0.f) * (&w0.x)[e];
        p0 += fmaxf(acc10[r], 0.f) * (&w1q.x)[e];
        p1 += fmaxf(acc11[r], 0.f) * (&w1q.x)[e];
      }
    }
    p0 += __shfl_xor(p0, 32);
    p1 += __shfl_xor(p1, 32);

    const int node = nbase + i;
    if (node < NODES) {
      float pv = hl ? p1 : p0;
      float sig = 1.0f / (1.0f + expf(-(pv + b2[node])));
      no_t[(size_t)node * BATCH + blockIdx.x * 256 + wv * 64 + lane] = sig;
    }

    if (i + 1 < NPG) __syncthreads();  // sW[0] staged for next node
  }
}

// ---- kernel 3: soft-decision-tree traversal --------------------------------

__global__ __launch_bounds__(256) void tree_kernel(
    const float* __restrict__ no_t,  // [255][8192]
    const float* __restrict__ leaf,  // [256]
    float* __restrict__ out)
{
  __shared__ float p[16][257];

  const int tid = threadIdx.x;
  const int bbase = blockIdx.x * 16;
  const int wave = tid >> 6;
  const int lane = tid & 63;

  for (int i = tid; i < NODES * 16; i += 256) {
    int n = i >> 4, r = i & 15;
    p[r][n] = no_t[(size_t)n * BATCH + bbase + r];
  }
  __syncthreads();

  float4 lw = ((const float4*)leaf)[lane];

  float* h_out  = out;
  float* pp_out = out + 8192;                            // [8192][256]
  float* no_out = out + 8192 + 8192 * 256;               // [8192][255]
  float* nr_out = out + 8192 + 8192 * 256 + 8192 * (size_t)NODES;  // [8192][255]

  for (int j = 0; j < 4; ++j) {
    const int r = wave * 4 + j;
    const int b = bbase + r;
    const float* pr = p[r];
    float* nr_b = nr_out + (size_t)b * NODES;

    float rc = 1.f;
#pragma unroll
    for (int L = 0; L < 6; ++L) {
      if (lane < (1 << L)) nr_b[(1 << L) - 1 + lane] = rc;
      float par = __shfl(rc, lane >> 1);
      float pv = pr[(1 << L) - 1 + (lane >> 1)];
      rc = par * ((lane & 1) ? pv : (1.f - pv));
    }
    nr_b[63 + lane] = rc;
    float p6 = pr[63 + lane];
    float r7a = rc * (1.f - p6), r7b = rc * p6;
    nr_b[127 + 2 * lane]     = r7a;
    nr_b[127 + 2 * lane + 1] = r7b;
    float p7a = pr[127 + 2 * lane], p7b = pr[127 + 2 * lane + 1];
    float4 pp;
    pp.x = r7a * (1.f - p7a);
    pp.y = r7a * p7a;
    pp.z = r7b * (1.f - p7b);
    pp.w = r7b * p7b;
    ((float4*)(pp_out + (size_t)b * 256))[lane] = pp;

    float* no_b = no_out + (size_t)b * NODES;
#pragma unroll
    for (int k = 0; k < 4; ++k) {
      int n = lane + 64 * k;
      if (n < NODES) no_b[n] = pr[n];
    }

    float hacc = pp.x * lw.x + pp.y * lw.y + pp.z * lw.z + pp.w * lw.w;
    hacc += __shfl_xor(hacc, 1);
    hacc += __shfl_xor(hacc, 2);
    hacc += __shfl_xor(hacc, 4);
    hacc += __shfl_xor(hacc, 8);
    hacc += __shfl_xor(hacc, 16);
    hacc += __shfl_xor(hacc, 32);
    if (lane == 0) h_out[b] = hacc;
  }
}

// ---- launcher --------------------------------------------------------------

extern "C" void kernel_launch(void* const* d_in, const int* in_sizes, int n_in,
                              void* d_out, int out_size, void* d_ws, size_t ws_size,
                              hipStream_t stream) {
  const float* x    = (const float*)d_in[0];
  const float* w1   = (const float*)d_in[1];
  const float* b1   = (const float*)d_in[2];
  const float* w2   = (const float*)d_in[3];
  const float* b2   = (const float*)d_in[4];
  const float* leaf = (const float*)d_in[5];
  float* out = (float*)d_out;

  // ws: xpack 4MB | w1pk 8MB (256-node pad; node 255 poison-but-finite) |
  //     w2p 64KB | b1p 64KB | no_t 8MB
  char* ws = (char*)d_ws;
  u16*   xpack = (u16*)ws;
  u16*   w1pk  = (u16*)(ws + (size_t)4194304);
  float* w2p   = (float*)(ws + (size_t)12582912);
  float* b1p   = (float*)(ws + (size_t)12648192);
  float* no_t  = (float*)(ws + (size_t)12713472);

  cvt_kernel<<<639, 256, 0, stream>>>(x, w1, b1, w2, xpack, w1pk, b1p, w2p);

  dim3 g(32, 64);  // 32 col-blocks (256 cols) x 64 node-groups (NPG=4) = 2048
  fused_mlp_kernel<<<g, 256, 0, stream>>>(xpack, w1pk, b1p, w2p, b2, no_t);

  tree_kernel<<<BATCH / 16, 256, 0, stream>>>(no_t, leaf, out);
}